// Round 14
// baseline (140.504 us; speedup 1.0000x reference)
//
#include <hip/hip_runtime.h>
#include <math.h>

// Shapes (from setup_inputs): B=2, N=512, C=256, H=128, W=224.
#define PTS 4     // points per MLP block
#define PX 16     // pixels per tile
#define CH 16     // gaussians per weight chunk
#define NTX 14    // tiles per row (W/PX)
#define NBLK 2048 // splat blocks (work-queue; ~5 resident/CU)

// ---------------- kernel 1: per-gaussian projection/prep ----------------
__global__ void prep_kernel(const float* __restrict__ gd,
                            const float* __restrict__ Kmat,
                            float4* __restrict__ bbox,
                            float4* __restrict__ prm,
                            int N, int B, float Wf, float Hf) {
  int i = blockIdx.x * blockDim.x + threadIdx.x;
  if (i >= B * N) return;
  int b = i / N;
  const float* g = gd + (size_t)i * 14;
  float X = g[0], Y = g[1], Z = g[2];
  float sigx = g[5], sigy = g[6], wt = g[12];
  const float* K = Kmat + (size_t)b * 9;
  float p0 = K[0]*X + K[1]*Y + K[2]*Z;
  float p1 = K[3]*X + K[4]*Y + K[5]*Z;
  float p2 = K[6]*X + K[7]*Y + K[8]*Z;
  float denom = p2 + 1e-6f;
  float p2x = p0 / denom, p2y = p1 / denom;
  float scale_x = Wf / K[2] * 0.5f;
  float scale_y = Hf / K[5] * 0.5f;
  float cx = p2x * scale_x;
  float cy = p2y * scale_y;
  bool valid = Z > 0.1f;
  bool inb = (cx >= 0.f) && (cx < Wf) && (cy >= 0.f) && (cy < Hf);
  bool active = valid && inb;
  float sxv = fmaxf(sigx * scale_x, 1.f);
  float syv = fmaxf(sigy * scale_y, 1.f);
  float wn = active ? wt : 0.f;
  float avg = 0.5f * (sxv + syv);
  if (active && wn != 0.f) {
    bbox[i] = make_float4(cx, cy, 3.f * sxv, 3.f * syv);
  } else {
    bbox[i] = make_float4(-1e30f, -1e30f, 0.f, 0.f);
  }
  prm[i] = make_float4(1.f / sxv, 1.f / syv, wn, avg);
}

// ---------------- kernel 2: MLP h = relu(pf@W1^T+b1)@W2^T+b2 ----------------
__global__ __launch_bounds__(256) void mlp_kernel(
    const float* __restrict__ pf, const float* __restrict__ W1,
    const float* __restrict__ b1, const float* __restrict__ W2,
    const float* __restrict__ b2, float* __restrict__ hout, int npts) {
  const int t = threadIdx.x;
  const int p0 = blockIdx.x * PTS;
  __shared__ __align__(16) float xs[PTS][256];

  const float4* pf4 = (const float4*)(pf + (size_t)p0 * 256);
  float4* xs4 = (float4*)&xs[0][0];
  #pragma unroll
  for (int i = 0; i < PTS * 64 / 256; ++i) xs4[t + 256 * i] = pf4[t + 256 * i];
  __syncthreads();

  float acc[PTS];
  float bb1 = b1[t];
  #pragma unroll
  for (int p = 0; p < PTS; ++p) acc[p] = bb1;
  const float* w1r = W1 + (size_t)t * 256;
  for (int k = 0; k < 256; k += 4) {
    float4 w = *(const float4*)(w1r + k);
    #pragma unroll
    for (int p = 0; p < PTS; ++p) {
      float4 x = *(const float4*)(&xs[p][k]);
      acc[p] += w.x * x.x + w.y * x.y + w.z * x.z + w.w * x.w;
    }
  }
  __syncthreads();
  #pragma unroll
  for (int p = 0; p < PTS; ++p) xs[p][t] = fmaxf(acc[p], 0.f);
  __syncthreads();

  float acc2[PTS];
  float bb2 = b2[t];
  #pragma unroll
  for (int p = 0; p < PTS; ++p) acc2[p] = bb2;
  const float* w2r = W2 + (size_t)t * 256;
  for (int k = 0; k < 256; k += 4) {
    float4 w = *(const float4*)(w2r + k);
    #pragma unroll
    for (int p = 0; p < PTS; ++p) {
      float4 x = *(const float4*)(&xs[p][k]);
      acc2[p] += w.x * x.x + w.y * x.y + w.z * x.z + w.w * x.w;
    }
  }
  #pragma unroll
  for (int p = 0; p < PTS; ++p)
    if (p0 + p < npts) hout[((size_t)(p0 + p)) * 256 + t] = acc2[p];
}

// ---------------- kernel 2b: fused row+tile cull (round-13, verified) -------
__global__ __launch_bounds__(256) void tilecull_kernel(
    const float4* __restrict__ bbox, int* __restrict__ tilelist,
    int* __restrict__ tilecnt, int* __restrict__ qhead,
    int N, int H, int W) {
  const int t = threadIdx.x;
  const int row = blockIdx.x;
  const int b = blockIdx.y;
  __shared__ int wcnt[4];
  __shared__ float xlo_s[512], xhi_s[512];
  __shared__ short gid_s[512];
  const float rf = (float)row;
  const float wmax = (float)(W - 1);
  const int lane = t & 63, wave = t >> 6;
  const unsigned long long lmask = (1ull << lane) - 1ull;
  const size_t bN = (size_t)b * N;

  if (t == 0 && row == 0 && b == 0) *qhead = NBLK;  // init work queue

  int rowlen = 0;
  for (int gb = 0; gb < N; gb += 256) {
    int g = gb + t;
    bool f = false;
    float bxlo = 0.f, bxhi = 0.f;
    if (g < N) {
      float4 bb = bbox[bN + g];
      bxlo = bb.x - bb.z; bxhi = bb.x + bb.z;
      f = (bb.y - bb.w <= rf) && (bb.y + bb.w >= rf) &&
          (bxhi >= 0.f) && (bxlo <= wmax);
    }
    unsigned long long m = __ballot(f);
    if (lane == 0) wcnt[wave] = __popcll(m);
    __syncthreads();
    int pre = 0;
    #pragma unroll
    for (int wv = 0; wv < 4; ++wv) pre += (wv < wave) ? wcnt[wv] : 0;
    int tot = wcnt[0] + wcnt[1] + wcnt[2] + wcnt[3];
    if (f) {
      int idx = rowlen + pre + __popcll(m & lmask);
      gid_s[idx] = (short)g; xlo_s[idx] = bxlo; xhi_s[idx] = bxhi;
    }
    __syncthreads();
    rowlen += tot;
  }

  for (int tx = wave; tx < NTX; tx += 4) {
    const float txlo = (float)(tx * PX), txhi = txlo + (float)(PX - 1);
    const size_t tid = ((size_t)b * H + row) * NTX + tx;
    int* out = tilelist + tid * 512;
    int cnt = 0;
    for (int rb = 0; rb < rowlen; rb += 64) {
      int i = rb + lane;
      bool f = false; int g = 0;
      if (i < rowlen) {
        f = (xhi_s[i] >= txlo) && (xlo_s[i] <= txhi);
        g = gid_s[i];
      }
      unsigned long long m = __ballot(f);
      if (f) out[cnt + __popcll(m & lmask)] = g;
      cnt += __popcll(m);
    }
    if (lane == 0) tilecnt[tid] = cnt;
  }
}

// ---------------- kernel 3: work-queue gather-splat --------------------------
// Unit = (tile, channel-half): 128 ch x 16 px. Dynamic atomic pop fixes the
// round-13 diagnosis (occupancy 11% = static mapping leaves a long serial
// tail on hot center tiles). Dens/unc computed redundantly by both halves
// (identical ascending glist order -> bitwise identical), written by half 0.
__global__ __launch_bounds__(256) void splat_kernel(
    const float4* __restrict__ bbox, const float4* __restrict__ prm,
    const float* __restrict__ hfeat,
    const int* __restrict__ tilelist, const int* __restrict__ tilecnt,
    int* __restrict__ qhead,
    float* __restrict__ fout, float* __restrict__ unc_out,
    float* __restrict__ dens_out, int N, int C, int H, int W, int nunits) {
  const int t = threadIdx.x;
  const int HW = H * W;

  __shared__ int glist[512];
  __shared__ __align__(16) float wlds[2][CH][PX];
  __shared__ __align__(16) float invd_s[PX];
  __shared__ float avgs_s[2][CH];
  __shared__ int unit_s;

  const int cg = t >> 2, pq = t & 3;      // 64 ch-pairs x 4 px-quads
  const int gi_w = t >> 4, j_w = t & 15;  // weight slot (16 g x 16 px)

  int unit = blockIdx.x;
  while (unit < nunits) {
    const int tileid = unit >> 1;
    const int chh = unit & 1;
    const int tx = tileid % NTX;
    const int rowb = tileid / NTX;
    const int row = rowb % H;
    const int b = rowb / H;
    const int x0 = tx * PX;
    const int chbase = chh << 7;
    const size_t bN = (size_t)b * N;
    const float rf = (float)row;
    const float xlo = (float)x0;
    const int cnt = tilecnt[tileid];

    float* fo = fout + ((size_t)(b * C + chbase + 2 * cg)) * HW
                     + (size_t)row * W + x0 + 4 * pq;

    if (cnt == 0) {
      if (chh == 0 && t < PX) {
        size_t pix = (size_t)b * HW + (size_t)row * W + x0 + t;
        dens_out[pix] = 1e-6f;
        unc_out[pix] = 0.f;
      }
      float4 z = make_float4(0.f, 0.f, 0.f, 0.f);
      *(float4*)(fo)      = z;
      *(float4*)(fo + HW) = z;
    } else {
      for (int i = t; i < cnt; i += 256) glist[i] = tilelist[(size_t)tileid * 512 + i];
      __syncthreads();

      float dreg = 0.f, ureg = 0.f;
      float4 a0 = make_float4(0.f, 0.f, 0.f, 0.f), a1 = a0;
      float2 hvA[CH], hvB[CH];
      const int nchunk = (cnt + CH - 1) / CH;

#define HV16(HV, CB) do { \
    int gn_ = cnt - (CB); \
    _Pragma("unroll") \
    for (int gi = 0; gi < CH; ++gi) { \
      int idx_ = (CB) + gi; if (idx_ > cnt - 1) idx_ = cnt - 1; \
      HV[gi] = (gi < gn_) ? *(const float2*)(hfeat + (bN + glist[idx_]) * (size_t)C + chbase + 2 * cg) \
                          : make_float2(0.f, 0.f); \
    } } while (0)

#define WGT16(BUF, CB) do { \
    float w_ = 0.f, av_ = 0.f; \
    int gn_ = cnt - (CB); \
    if (gi_w < gn_) { \
      int g_ = glist[(CB) + gi_w]; \
      float4 bb_ = bbox[bN + g_]; \
      float4 pr_ = prm[bN + g_]; \
      float dx_ = (xlo + (float)j_w - bb_.x) * pr_.x; \
      float dy_ = (rf - bb_.y) * pr_.y; \
      float q_ = dx_ * dx_ + dy_ * dy_; \
      w_ = (q_ < 9.f) ? __expf(-0.5f * q_) * pr_.z : 0.f; \
      av_ = pr_.w; \
    } \
    wlds[BUF][gi_w][j_w] = w_; \
    if (j_w == 0) avgs_s[BUF][gi_w] = av_; } while (0)

#define DENS16(BUF, GC) do { \
    if (t < PX) { \
      for (int gi = 0; gi < (GC); ++gi) { \
        float w = wlds[BUF][gi][t]; \
        dreg += w; ureg += w * avgs_s[BUF][gi]; \
      } } } while (0)

#define FMA16(BUF, HV) do { \
    const float4* wr_ = (const float4*)&wlds[BUF][0][0]; \
    _Pragma("unroll") \
    for (int gi = 0; gi < CH; ++gi) { \
      float4 w = wr_[gi * 4 + pq]; \
      float2 h = HV[gi]; \
      a0.x += w.x*h.x; a0.y += w.y*h.x; a0.z += w.z*h.x; a0.w += w.w*h.x; \
      a1.x += w.x*h.y; a1.y += w.y*h.y; a1.z += w.z*h.y; a1.w += w.w*h.y; \
    } } while (0)

      HV16(hvA, 0);
      WGT16(0, 0);
      __syncthreads();
      for (int c = 0; c < nchunk; c += 2) {
        {
          const int gc = min(CH, cnt - c * CH);
          HV16(hvB, (c + 1) * CH);
          WGT16(1, (c + 1) * CH);
          DENS16(0, gc);
          FMA16(0, hvA);
          __syncthreads();
        }
        if (c + 1 < nchunk) {
          const int gc = min(CH, cnt - (c + 1) * CH);
          HV16(hvA, (c + 2) * CH);
          WGT16(0, (c + 2) * CH);
          DENS16(1, gc);
          FMA16(1, hvB);
          __syncthreads();
        }
      }

      if (t < PX) {
        float dc = fmaxf(dreg, 1e-6f);
        float inv = 1.f / dc;
        invd_s[t] = inv;
        if (chh == 0) {
          size_t pix = (size_t)b * HW + (size_t)row * W + x0 + t;
          dens_out[pix] = dc;
          unc_out[pix] = ureg * inv;
        }
      }
      __syncthreads();

      float4 iq = *(const float4*)&invd_s[4 * pq];
      *(float4*)(fo)      = make_float4(a0.x*iq.x, a0.y*iq.y, a0.z*iq.z, a0.w*iq.w);
      *(float4*)(fo + HW) = make_float4(a1.x*iq.x, a1.y*iq.y, a1.z*iq.z, a1.w*iq.w);

#undef HV16
#undef WGT16
#undef DENS16
#undef FMA16
    }

    // ---- pop next unit (also fences shared reuse) ----
    __syncthreads();
    if (t == 0) unit_s = atomicAdd(qhead, 1);
    __syncthreads();
    unit = unit_s;
  }
}

extern "C" void kernel_launch(void* const* d_in, const int* in_sizes, int n_in,
                              void* d_out, int out_size, void* d_ws, size_t ws_size,
                              hipStream_t stream) {
  const float* pf = (const float*)d_in[0];
  const float* gd = (const float*)d_in[1];
  const float* K  = (const float*)d_in[2];
  const float* W1 = (const float*)d_in[3];
  const float* b1 = (const float*)d_in[4];
  const float* W2 = (const float*)d_in[5];
  const float* b2 = (const float*)d_in[6];

  const int B = in_sizes[2] / 9;
  const int N = in_sizes[1] / (B * 14);
  const int C = in_sizes[0] / (B * N);
  const int H = 128, W = 224;
  const int ntiles = B * H * NTX;
  const int nunits = ntiles * 2;

  char* wsb = (char*)d_ws;
  size_t off = 0;
  float4* bbox = (float4*)(wsb + off); off += (size_t)B * N * sizeof(float4);
  float4* prm  = (float4*)(wsb + off); off += (size_t)B * N * sizeof(float4);
  float*  hfe  = (float*)(wsb + off);  off += (size_t)B * N * C * 4;
  int* tilelist = (int*)(wsb + off);   off += (size_t)ntiles * 512 * 4;
  int* tilecnt  = (int*)(wsb + off);   off += (size_t)ntiles * 4;
  int* qhead    = (int*)(wsb + off);   off += 16;

  float* out      = (float*)d_out;
  float* unc_out  = out + (size_t)B * C * H * W;
  float* dens_out = unc_out + (size_t)B * H * W;

  prep_kernel<<<dim3((B * N + 255) / 256), 256, 0, stream>>>(
      gd, K, bbox, prm, N, B, (float)W, (float)H);
  tilecull_kernel<<<dim3(H, B), 256, 0, stream>>>(
      bbox, tilelist, tilecnt, qhead, N, H, W);
  mlp_kernel<<<dim3((B * N + PTS - 1) / PTS), 256, 0, stream>>>(
      pf, W1, b1, W2, b2, hfe, B * N);
  splat_kernel<<<dim3(NBLK), 256, 0, stream>>>(
      bbox, prm, hfe, tilelist, tilecnt, qhead, out, unc_out, dens_out,
      N, C, H, W, nunits);
}

// Round 15
// 102.791 us; speedup vs baseline: 1.3669x; 1.3669x over previous
//
#include <hip/hip_runtime.h>
#include <math.h>

// Shapes (from setup_inputs): B=2, N=512, C=256, H=128, W=224.
#define PTS 4     // points per MLP block
#define PX 16     // pixels per tile
#define NTX 14    // tiles per row (W/PX)

// ---------------- kernel 1: per-gaussian projection/prep ----------------
__global__ void prep_kernel(const float* __restrict__ gd,
                            const float* __restrict__ Kmat,
                            float4* __restrict__ bbox,
                            float4* __restrict__ prm,
                            int N, int B, float Wf, float Hf) {
  int i = blockIdx.x * blockDim.x + threadIdx.x;
  if (i >= B * N) return;
  int b = i / N;
  const float* g = gd + (size_t)i * 14;
  float X = g[0], Y = g[1], Z = g[2];
  float sigx = g[5], sigy = g[6], wt = g[12];
  const float* K = Kmat + (size_t)b * 9;
  float p0 = K[0]*X + K[1]*Y + K[2]*Z;
  float p1 = K[3]*X + K[4]*Y + K[5]*Z;
  float p2 = K[6]*X + K[7]*Y + K[8]*Z;
  float denom = p2 + 1e-6f;
  float p2x = p0 / denom, p2y = p1 / denom;
  float scale_x = Wf / K[2] * 0.5f;
  float scale_y = Hf / K[5] * 0.5f;
  float cx = p2x * scale_x;
  float cy = p2y * scale_y;
  bool valid = Z > 0.1f;
  bool inb = (cx >= 0.f) && (cx < Wf) && (cy >= 0.f) && (cy < Hf);
  bool active = valid && inb;
  float sxv = fmaxf(sigx * scale_x, 1.f);
  float syv = fmaxf(sigy * scale_y, 1.f);
  float wn = active ? wt : 0.f;
  float avg = 0.5f * (sxv + syv);
  if (active && wn != 0.f) {
    bbox[i] = make_float4(cx, cy, 3.f * sxv, 3.f * syv);
  } else {
    bbox[i] = make_float4(-1e30f, -1e30f, 0.f, 0.f);
  }
  prm[i] = make_float4(1.f / sxv, 1.f / syv, wn, avg);
}

// ---------------- kernel 2: MLP h = relu(pf@W1^T+b1)@W2^T+b2 ----------------
__global__ __launch_bounds__(256) void mlp_kernel(
    const float* __restrict__ pf, const float* __restrict__ W1,
    const float* __restrict__ b1, const float* __restrict__ W2,
    const float* __restrict__ b2, float* __restrict__ hout, int npts) {
  const int t = threadIdx.x;
  const int p0 = blockIdx.x * PTS;
  __shared__ __align__(16) float xs[PTS][256];

  const float4* pf4 = (const float4*)(pf + (size_t)p0 * 256);
  float4* xs4 = (float4*)&xs[0][0];
  #pragma unroll
  for (int i = 0; i < PTS * 64 / 256; ++i) xs4[t + 256 * i] = pf4[t + 256 * i];
  __syncthreads();

  float acc[PTS];
  float bb1 = b1[t];
  #pragma unroll
  for (int p = 0; p < PTS; ++p) acc[p] = bb1;
  const float* w1r = W1 + (size_t)t * 256;
  for (int k = 0; k < 256; k += 4) {
    float4 w = *(const float4*)(w1r + k);
    #pragma unroll
    for (int p = 0; p < PTS; ++p) {
      float4 x = *(const float4*)(&xs[p][k]);
      acc[p] += w.x * x.x + w.y * x.y + w.z * x.z + w.w * x.w;
    }
  }
  __syncthreads();
  #pragma unroll
  for (int p = 0; p < PTS; ++p) xs[p][t] = fmaxf(acc[p], 0.f);
  __syncthreads();

  float acc2[PTS];
  float bb2 = b2[t];
  #pragma unroll
  for (int p = 0; p < PTS; ++p) acc2[p] = bb2;
  const float* w2r = W2 + (size_t)t * 256;
  for (int k = 0; k < 256; k += 4) {
    float4 w = *(const float4*)(w2r + k);
    #pragma unroll
    for (int p = 0; p < PTS; ++p) {
      float4 x = *(const float4*)(&xs[p][k]);
      acc2[p] += w.x * x.x + w.y * x.y + w.z * x.z + w.w * x.w;
    }
  }
  #pragma unroll
  for (int p = 0; p < PTS; ++p)
    if (p0 + p < npts) hout[((size_t)(p0 + p)) * 256 + t] = acc2[p];
}

// ---------------- kernel 2b: fused row+tile cull (round-13, verified) -------
__global__ __launch_bounds__(256) void tilecull_kernel(
    const float4* __restrict__ bbox, int* __restrict__ tilelist,
    int* __restrict__ tilecnt, int N, int H, int W) {
  const int t = threadIdx.x;
  const int row = blockIdx.x;
  const int b = blockIdx.y;
  __shared__ int wcnt[4];
  __shared__ float xlo_s[512], xhi_s[512];
  __shared__ short gid_s[512];
  const float rf = (float)row;
  const float wmax = (float)(W - 1);
  const int lane = t & 63, wave = t >> 6;
  const unsigned long long lmask = (1ull << lane) - 1ull;
  const size_t bN = (size_t)b * N;

  int rowlen = 0;
  for (int gb = 0; gb < N; gb += 256) {
    int g = gb + t;
    bool f = false;
    float bxlo = 0.f, bxhi = 0.f;
    if (g < N) {
      float4 bb = bbox[bN + g];
      bxlo = bb.x - bb.z; bxhi = bb.x + bb.z;
      f = (bb.y - bb.w <= rf) && (bb.y + bb.w >= rf) &&
          (bxhi >= 0.f) && (bxlo <= wmax);
    }
    unsigned long long m = __ballot(f);
    if (lane == 0) wcnt[wave] = __popcll(m);
    __syncthreads();
    int pre = 0;
    #pragma unroll
    for (int wv = 0; wv < 4; ++wv) pre += (wv < wave) ? wcnt[wv] : 0;
    int tot = wcnt[0] + wcnt[1] + wcnt[2] + wcnt[3];
    if (f) {
      int idx = rowlen + pre + __popcll(m & lmask);
      gid_s[idx] = (short)g; xlo_s[idx] = bxlo; xhi_s[idx] = bxhi;
    }
    __syncthreads();
    rowlen += tot;
  }

  for (int tx = wave; tx < NTX; tx += 4) {
    const float txlo = (float)(tx * PX), txhi = txlo + (float)(PX - 1);
    const size_t tid = ((size_t)b * H + row) * NTX + tx;
    int* out = tilelist + tid * 512;
    int cnt = 0;
    for (int rb = 0; rb < rowlen; rb += 64) {
      int i = rb + lane;
      bool f = false; int g = 0;
      if (i < rowlen) {
        f = (xhi_s[i] >= txlo) && (xlo_s[i] <= txhi);
        g = gid_s[i];
      }
      unsigned long long m = __ballot(f);
      if (f) out[cnt + __popcll(m & lmask)] = g;
      cnt += __popcll(m);
    }
    if (lane == 0) tilecnt[tid] = cnt;
  }
}

// ---------------- kernel 3: wave-autonomous splat ----------------------------
// Unit = (tile, channel-half) = 16px x 128ch; ONE WAVE per unit (14336 waves,
// grid 3584x256). NO barriers, NO LDS, no queue: rounds 6-14 proved every
// block-level structure is latency-chain-bound with ~2 blocks/CU effective;
// the only fast kernel (untile, ~4.5TB/s) was barrier-free with fat ILP.
// Lane = (px in 16, cq in 4) owns 32 channels; per gaussian: 1 exp + 8
// broadcast float4 hv loads + 32 FMA; meta prefetched 1 ahead; dens/unc by
// the cq==0 lanes in ascending glist order (deterministic), written by half 0.
__global__ __launch_bounds__(256) void splatw_kernel(
    const float4* __restrict__ bbox, const float4* __restrict__ prm,
    const float* __restrict__ hfeat,
    const int* __restrict__ tilelist, const int* __restrict__ tilecnt,
    float* __restrict__ fout, float* __restrict__ unc_out,
    float* __restrict__ dens_out, int N, int C, int H, int W, int nunits) {
  const int t = threadIdx.x;
  const int wv = t >> 6, lane = t & 63;
  const int unit = blockIdx.x * 4 + wv;
  if (unit >= nunits) return;

  const int tileid = unit >> 1;
  const int half = unit & 1;
  const int tx = tileid % NTX;
  const int rowb = tileid / NTX;
  const int row = rowb % H;
  const int b = rowb / H;
  const int x0 = tx * PX;
  const int HW = H * W;

  const int px = lane & 15;
  const int cq = lane >> 4;                 // 0..3
  const int ch0 = half * 128 + cq * 32;     // this lane's 32 channels

  const size_t bN = (size_t)b * N;
  const float rf = (float)row;
  const float pxf = (float)(x0 + px);
  const int cnt = tilecnt[tileid];
  const int* gl = tilelist + (size_t)tileid * 512;

  float4 a0 = make_float4(0.f,0.f,0.f,0.f), a1 = a0, a2 = a0, a3 = a0;
  float4 a4 = a0, a5 = a0, a6 = a0, a7 = a0;
  float dreg = 0.f, ureg = 0.f;

  if (cnt > 0) {
    // prefetched meta for gaussian i
    int g = gl[0];
    float4 bb = bbox[bN + g];
    float4 pr = prm[bN + g];
    for (int i = 0; i < cnt; ++i) {
      // issue next meta early (independent of this iteration's math)
      int gn = (i + 1 < cnt) ? gl[i + 1] : g;
      float4 bbn = bbox[bN + gn];
      float4 prn = prm[bN + gn];

      const float4* hp = (const float4*)(hfeat + (bN + g) * (size_t)C + ch0);
      float4 h0 = hp[0], h1 = hp[1], h2 = hp[2], h3 = hp[3];
      float4 h4 = hp[4], h5 = hp[5], h6 = hp[6], h7 = hp[7];

      float dx = (pxf - bb.x) * pr.x;
      float dy = (rf - bb.y) * pr.y;
      float q = dx * dx + dy * dy;
      float w = (q < 9.f) ? __expf(-0.5f * q) * pr.z : 0.f;
      dreg += w; ureg += w * pr.w;

      a0.x += w*h0.x; a0.y += w*h0.y; a0.z += w*h0.z; a0.w += w*h0.w;
      a1.x += w*h1.x; a1.y += w*h1.y; a1.z += w*h1.z; a1.w += w*h1.w;
      a2.x += w*h2.x; a2.y += w*h2.y; a2.z += w*h2.z; a2.w += w*h2.w;
      a3.x += w*h3.x; a3.y += w*h3.y; a3.z += w*h3.z; a3.w += w*h3.w;
      a4.x += w*h4.x; a4.y += w*h4.y; a4.z += w*h4.z; a4.w += w*h4.w;
      a5.x += w*h5.x; a5.y += w*h5.y; a5.z += w*h5.z; a5.w += w*h5.w;
      a6.x += w*h6.x; a6.y += w*h6.y; a6.z += w*h6.z; a6.w += w*h6.w;
      a7.x += w*h7.x; a7.y += w*h7.y; a7.z += w*h7.z; a7.w += w*h7.w;

      g = gn; bb = bbn; pr = prn;
    }
  }

  const float dc = fmaxf(dreg, 1e-6f);
  const float iv = 1.f / dc;
  if (half == 0 && cq == 0) {
    size_t pix = (size_t)b * HW + (size_t)row * W + x0 + px;
    dens_out[pix] = dc;
    unc_out[pix] = ureg * iv;
  }

  float* fo = fout + ((size_t)(b * C + ch0)) * HW + (size_t)row * W + x0 + px;
  const size_t s = (size_t)HW;
  fo[0]      = a0.x*iv; fo[s]      = a0.y*iv; fo[2*s]  = a0.z*iv; fo[3*s]  = a0.w*iv;
  fo[4*s]    = a1.x*iv; fo[5*s]    = a1.y*iv; fo[6*s]  = a1.z*iv; fo[7*s]  = a1.w*iv;
  fo[8*s]    = a2.x*iv; fo[9*s]    = a2.y*iv; fo[10*s] = a2.z*iv; fo[11*s] = a2.w*iv;
  fo[12*s]   = a3.x*iv; fo[13*s]   = a3.y*iv; fo[14*s] = a3.z*iv; fo[15*s] = a3.w*iv;
  fo[16*s]   = a4.x*iv; fo[17*s]   = a4.y*iv; fo[18*s] = a4.z*iv; fo[19*s] = a4.w*iv;
  fo[20*s]   = a5.x*iv; fo[21*s]   = a5.y*iv; fo[22*s] = a5.z*iv; fo[23*s] = a5.w*iv;
  fo[24*s]   = a6.x*iv; fo[25*s]   = a6.y*iv; fo[26*s] = a6.z*iv; fo[27*s] = a6.w*iv;
  fo[28*s]   = a7.x*iv; fo[29*s]   = a7.y*iv; fo[30*s] = a7.z*iv; fo[31*s] = a7.w*iv;
}

extern "C" void kernel_launch(void* const* d_in, const int* in_sizes, int n_in,
                              void* d_out, int out_size, void* d_ws, size_t ws_size,
                              hipStream_t stream) {
  const float* pf = (const float*)d_in[0];
  const float* gd = (const float*)d_in[1];
  const float* K  = (const float*)d_in[2];
  const float* W1 = (const float*)d_in[3];
  const float* b1 = (const float*)d_in[4];
  const float* W2 = (const float*)d_in[5];
  const float* b2 = (const float*)d_in[6];

  const int B = in_sizes[2] / 9;
  const int N = in_sizes[1] / (B * 14);
  const int C = in_sizes[0] / (B * N);
  const int H = 128, W = 224;
  const int ntiles = B * H * NTX;
  const int nunits = ntiles * 2;

  char* wsb = (char*)d_ws;
  size_t off = 0;
  float4* bbox = (float4*)(wsb + off); off += (size_t)B * N * sizeof(float4);
  float4* prm  = (float4*)(wsb + off); off += (size_t)B * N * sizeof(float4);
  float*  hfe  = (float*)(wsb + off);  off += (size_t)B * N * C * 4;
  int* tilelist = (int*)(wsb + off);   off += (size_t)ntiles * 512 * 4;
  int* tilecnt  = (int*)(wsb + off);   off += (size_t)ntiles * 4;

  float* out      = (float*)d_out;
  float* unc_out  = out + (size_t)B * C * H * W;
  float* dens_out = unc_out + (size_t)B * H * W;

  prep_kernel<<<dim3((B * N + 255) / 256), 256, 0, stream>>>(
      gd, K, bbox, prm, N, B, (float)W, (float)H);
  tilecull_kernel<<<dim3(H, B), 256, 0, stream>>>(
      bbox, tilelist, tilecnt, N, H, W);
  mlp_kernel<<<dim3((B * N + PTS - 1) / PTS), 256, 0, stream>>>(
      pf, W1, b1, W2, b2, hfe, B * N);
  splatw_kernel<<<dim3((nunits + 3) / 4), 256, 0, stream>>>(
      bbox, prm, hfe, tilelist, tilecnt, out, unc_out, dens_out,
      N, C, H, W, nunits);
}

// Round 16
// 93.333 us; speedup vs baseline: 1.5054x; 1.1013x over previous
//
#include <hip/hip_runtime.h>
#include <math.h>

// Shapes (from setup_inputs): B=2, N=512, C=256, H=128, W=224.
#define PTS 4     // points per MLP block
#define PX 16     // pixels per tile
#define NTX 14    // tiles per row (W/PX)

// ---------------- kernel 1: per-gaussian projection/prep ----------------
__global__ void prep_kernel(const float* __restrict__ gd,
                            const float* __restrict__ Kmat,
                            float4* __restrict__ bbox,
                            float4* __restrict__ prm,
                            int N, int B, float Wf, float Hf) {
  int i = blockIdx.x * blockDim.x + threadIdx.x;
  if (i >= B * N) return;
  int b = i / N;
  const float* g = gd + (size_t)i * 14;
  float X = g[0], Y = g[1], Z = g[2];
  float sigx = g[5], sigy = g[6], wt = g[12];
  const float* K = Kmat + (size_t)b * 9;
  float p0 = K[0]*X + K[1]*Y + K[2]*Z;
  float p1 = K[3]*X + K[4]*Y + K[5]*Z;
  float p2 = K[6]*X + K[7]*Y + K[8]*Z;
  float denom = p2 + 1e-6f;
  float p2x = p0 / denom, p2y = p1 / denom;
  float scale_x = Wf / K[2] * 0.5f;
  float scale_y = Hf / K[5] * 0.5f;
  float cx = p2x * scale_x;
  float cy = p2y * scale_y;
  bool valid = Z > 0.1f;
  bool inb = (cx >= 0.f) && (cx < Wf) && (cy >= 0.f) && (cy < Hf);
  bool active = valid && inb;
  float sxv = fmaxf(sigx * scale_x, 1.f);
  float syv = fmaxf(sigy * scale_y, 1.f);
  float wn = active ? wt : 0.f;
  float avg = 0.5f * (sxv + syv);
  if (active && wn != 0.f) {
    bbox[i] = make_float4(cx, cy, 3.f * sxv, 3.f * syv);
  } else {
    bbox[i] = make_float4(-1e30f, -1e30f, 0.f, 0.f);
  }
  prm[i] = make_float4(1.f / sxv, 1.f / syv, wn, avg);
}

// ---------------- kernel 2: MLP h = relu(pf@W1^T+b1)@W2^T+b2 ----------------
__global__ __launch_bounds__(256) void mlp_kernel(
    const float* __restrict__ pf, const float* __restrict__ W1,
    const float* __restrict__ b1, const float* __restrict__ W2,
    const float* __restrict__ b2, float* __restrict__ hout, int npts) {
  const int t = threadIdx.x;
  const int p0 = blockIdx.x * PTS;
  __shared__ __align__(16) float xs[PTS][256];

  const float4* pf4 = (const float4*)(pf + (size_t)p0 * 256);
  float4* xs4 = (float4*)&xs[0][0];
  #pragma unroll
  for (int i = 0; i < PTS * 64 / 256; ++i) xs4[t + 256 * i] = pf4[t + 256 * i];
  __syncthreads();

  float acc[PTS];
  float bb1 = b1[t];
  #pragma unroll
  for (int p = 0; p < PTS; ++p) acc[p] = bb1;
  const float* w1r = W1 + (size_t)t * 256;
  for (int k = 0; k < 256; k += 4) {
    float4 w = *(const float4*)(w1r + k);
    #pragma unroll
    for (int p = 0; p < PTS; ++p) {
      float4 x = *(const float4*)(&xs[p][k]);
      acc[p] += w.x * x.x + w.y * x.y + w.z * x.z + w.w * x.w;
    }
  }
  __syncthreads();
  #pragma unroll
  for (int p = 0; p < PTS; ++p) xs[p][t] = fmaxf(acc[p], 0.f);
  __syncthreads();

  float acc2[PTS];
  float bb2 = b2[t];
  #pragma unroll
  for (int p = 0; p < PTS; ++p) acc2[p] = bb2;
  const float* w2r = W2 + (size_t)t * 256;
  for (int k = 0; k < 256; k += 4) {
    float4 w = *(const float4*)(w2r + k);
    #pragma unroll
    for (int p = 0; p < PTS; ++p) {
      float4 x = *(const float4*)(&xs[p][k]);
      acc2[p] += w.x * x.x + w.y * x.y + w.z * x.z + w.w * x.w;
    }
  }
  #pragma unroll
  for (int p = 0; p < PTS; ++p)
    if (p0 + p < npts) hout[((size_t)(p0 + p)) * 256 + t] = acc2[p];
}

// ---------------- kernel 2b: fused row+tile cull (round-13, verified) -------
__global__ __launch_bounds__(256) void tilecull_kernel(
    const float4* __restrict__ bbox, int* __restrict__ tilelist,
    int* __restrict__ tilecnt, int N, int H, int W) {
  const int t = threadIdx.x;
  const int row = blockIdx.x;
  const int b = blockIdx.y;
  __shared__ int wcnt[4];
  __shared__ float xlo_s[512], xhi_s[512];
  __shared__ short gid_s[512];
  const float rf = (float)row;
  const float wmax = (float)(W - 1);
  const int lane = t & 63, wave = t >> 6;
  const unsigned long long lmask = (1ull << lane) - 1ull;
  const size_t bN = (size_t)b * N;

  int rowlen = 0;
  for (int gb = 0; gb < N; gb += 256) {
    int g = gb + t;
    bool f = false;
    float bxlo = 0.f, bxhi = 0.f;
    if (g < N) {
      float4 bb = bbox[bN + g];
      bxlo = bb.x - bb.z; bxhi = bb.x + bb.z;
      f = (bb.y - bb.w <= rf) && (bb.y + bb.w >= rf) &&
          (bxhi >= 0.f) && (bxlo <= wmax);
    }
    unsigned long long m = __ballot(f);
    if (lane == 0) wcnt[wave] = __popcll(m);
    __syncthreads();
    int pre = 0;
    #pragma unroll
    for (int wv = 0; wv < 4; ++wv) pre += (wv < wave) ? wcnt[wv] : 0;
    int tot = wcnt[0] + wcnt[1] + wcnt[2] + wcnt[3];
    if (f) {
      int idx = rowlen + pre + __popcll(m & lmask);
      gid_s[idx] = (short)g; xlo_s[idx] = bxlo; xhi_s[idx] = bxhi;
    }
    __syncthreads();
    rowlen += tot;
  }

  for (int tx = wave; tx < NTX; tx += 4) {
    const float txlo = (float)(tx * PX), txhi = txlo + (float)(PX - 1);
    const size_t tid = ((size_t)b * H + row) * NTX + tx;
    int* out = tilelist + tid * 512;
    int cnt = 0;
    for (int rb = 0; rb < rowlen; rb += 64) {
      int i = rb + lane;
      bool f = false; int g = 0;
      if (i < rowlen) {
        f = (xhi_s[i] >= txlo) && (xlo_s[i] <= txhi);
        g = gid_s[i];
      }
      unsigned long long m = __ballot(f);
      if (f) out[cnt + __popcll(m & lmask)] = g;
      cnt += __popcll(m);
    }
    if (lane == 0) tilecnt[tid] = cnt;
  }
}

// ---------------- kernel 3: barrier-free block-per-tile splat ---------------
// One 256-thread block per tile (grid 14 x 128 x 2, rows dispatched
// center-out so hot tiles start first). Thread = 4ch x 4px, 16 named accs.
// ZERO barriers, ZERO LDS -> loads stay in flight (R7/R13: __syncthreads
// drains vmcnt, exposing full L2 latency per chunk — the hot-tile tail that
// pinned every variant at 45-55us). 2-gaussian-deep software pipeline on
// meta+hv. Dens/unc accumulated redundantly per-thread (w_j identical across
// channel groups) -> no cross-thread communication; cnt==0 uses same path.
__global__ __launch_bounds__(256) void splat_kernel(
    const float4* __restrict__ bbox, const float4* __restrict__ prm,
    const float4* __restrict__ hf4,
    const int* __restrict__ tilelist, const int* __restrict__ tilecnt,
    float* __restrict__ fout, float* __restrict__ unc_out,
    float* __restrict__ dens_out, int N, int C, int H, int W) {
  const int t = threadIdx.x;
  const int tx = blockIdx.x;
  const int ri = blockIdx.y;
  const int row = (ri & 1) ? 63 - (ri >> 1) : 64 + (ri >> 1);  // center-out
  const int b = blockIdx.z;
  const int x0 = tx * PX;
  const int HW = H * W;

  const int cg = t >> 2, pq = t & 3;
  const float pxb = (float)(x0 + 4 * pq);
  const float rf = (float)row;
  const size_t bN = (size_t)b * N;
  const int tileid = (b * H + row) * NTX + tx;
  const int cnt = tilecnt[tileid];

  float4 acc0 = make_float4(0.f,0.f,0.f,0.f);  // pixel pxb+0, 4 channels
  float4 acc1 = acc0, acc2 = acc0, acc3 = acc0;
  float d0 = 0.f, d1 = 0.f, d2 = 0.f, d3 = 0.f;
  float u0 = 0.f, u1 = 0.f, u2 = 0.f, u3 = 0.f;

#define COMPUTE(BB, PR, HV) do { \
    float dy_ = (rf - BB.y) * PR.y; \
    float dy2_ = dy_ * dy_; \
    float dx0_ = (pxb + 0.f - BB.x) * PR.x; float q0_ = dx0_*dx0_ + dy2_; \
    float dx1_ = (pxb + 1.f - BB.x) * PR.x; float q1_ = dx1_*dx1_ + dy2_; \
    float dx2_ = (pxb + 2.f - BB.x) * PR.x; float q2_ = dx2_*dx2_ + dy2_; \
    float dx3_ = (pxb + 3.f - BB.x) * PR.x; float q3_ = dx3_*dx3_ + dy2_; \
    float w0_ = (q0_ < 9.f) ? __expf(-0.5f * q0_) * PR.z : 0.f; \
    float w1_ = (q1_ < 9.f) ? __expf(-0.5f * q1_) * PR.z : 0.f; \
    float w2_ = (q2_ < 9.f) ? __expf(-0.5f * q2_) * PR.z : 0.f; \
    float w3_ = (q3_ < 9.f) ? __expf(-0.5f * q3_) * PR.z : 0.f; \
    d0 += w0_; d1 += w1_; d2 += w2_; d3 += w3_; \
    u0 += w0_ * PR.w; u1 += w1_ * PR.w; u2 += w2_ * PR.w; u3 += w3_ * PR.w; \
    acc0.x += w0_*HV.x; acc0.y += w0_*HV.y; acc0.z += w0_*HV.z; acc0.w += w0_*HV.w; \
    acc1.x += w1_*HV.x; acc1.y += w1_*HV.y; acc1.z += w1_*HV.z; acc1.w += w1_*HV.w; \
    acc2.x += w2_*HV.x; acc2.y += w2_*HV.y; acc2.z += w2_*HV.z; acc2.w += w2_*HV.w; \
    acc3.x += w3_*HV.x; acc3.y += w3_*HV.y; acc3.z += w3_*HV.z; acc3.w += w3_*HV.w; \
  } while (0)

  if (cnt > 0) {
    const int* gl = tilelist + (size_t)tileid * 512;
    const int C4 = C >> 2;
    int ga = gl[0];
    int gb_ = gl[cnt > 1 ? 1 : 0];
    float4 bbA = bbox[bN + ga], prA = prm[bN + ga];
    float4 hvA = hf4[(bN + ga) * C4 + cg];
    float4 bbB = bbox[bN + gb_], prB = prm[bN + gb_];
    float4 hvB = hf4[(bN + gb_) * C4 + cg];

    for (int i = 0; i < cnt; ) {
      {
        int ip = (i + 2 < cnt) ? i + 2 : cnt - 1;
        int gp = gl[ip];
        float4 nbb = bbox[bN + gp], npr = prm[bN + gp];
        float4 nhv = hf4[(bN + gp) * C4 + cg];
        COMPUTE(bbA, prA, hvA);
        bbA = nbb; prA = npr; hvA = nhv;
      }
      ++i; if (i >= cnt) break;
      {
        int ip = (i + 2 < cnt) ? i + 2 : cnt - 1;
        int gp = gl[ip];
        float4 nbb = bbox[bN + gp], npr = prm[bN + gp];
        float4 nhv = hf4[(bN + gp) * C4 + cg];
        COMPUTE(bbB, prB, hvB);
        bbB = nbb; prB = npr; hvB = nhv;
      }
      ++i;
    }
  }
#undef COMPUTE

  const float dc0 = fmaxf(d0, 1e-6f), dc1 = fmaxf(d1, 1e-6f);
  const float dc2 = fmaxf(d2, 1e-6f), dc3 = fmaxf(d3, 1e-6f);
  const float i0 = 1.f / dc0, i1 = 1.f / dc1, i2 = 1.f / dc2, i3 = 1.f / dc3;

  if (cg == 0) {
    size_t pix = (size_t)b * HW + (size_t)row * W + x0 + 4 * pq;
    *(float4*)(dens_out + pix) = make_float4(dc0, dc1, dc2, dc3);
    *(float4*)(unc_out + pix)  = make_float4(u0*i0, u1*i1, u2*i2, u3*i3);
  }

  float* fo = fout + ((size_t)(b * C + 4 * cg)) * HW + (size_t)row * W + x0 + 4 * pq;
  *(float4*)(fo)          = make_float4(acc0.x*i0, acc1.x*i1, acc2.x*i2, acc3.x*i3);
  *(float4*)(fo + HW)     = make_float4(acc0.y*i0, acc1.y*i1, acc2.y*i2, acc3.y*i3);
  *(float4*)(fo + 2*HW)   = make_float4(acc0.z*i0, acc1.z*i1, acc2.z*i2, acc3.z*i3);
  *(float4*)(fo + 3*HW)   = make_float4(acc0.w*i0, acc1.w*i1, acc2.w*i2, acc3.w*i3);
}

extern "C" void kernel_launch(void* const* d_in, const int* in_sizes, int n_in,
                              void* d_out, int out_size, void* d_ws, size_t ws_size,
                              hipStream_t stream) {
  const float* pf = (const float*)d_in[0];
  const float* gd = (const float*)d_in[1];
  const float* K  = (const float*)d_in[2];
  const float* W1 = (const float*)d_in[3];
  const float* b1 = (const float*)d_in[4];
  const float* W2 = (const float*)d_in[5];
  const float* b2 = (const float*)d_in[6];

  const int B = in_sizes[2] / 9;
  const int N = in_sizes[1] / (B * 14);
  const int C = in_sizes[0] / (B * N);
  const int H = 128, W = 224;
  const int ntiles = B * H * NTX;

  char* wsb = (char*)d_ws;
  size_t off = 0;
  float4* bbox = (float4*)(wsb + off); off += (size_t)B * N * sizeof(float4);
  float4* prm  = (float4*)(wsb + off); off += (size_t)B * N * sizeof(float4);
  float*  hfe  = (float*)(wsb + off);  off += (size_t)B * N * C * 4;
  int* tilelist = (int*)(wsb + off);   off += (size_t)ntiles * 512 * 4;
  int* tilecnt  = (int*)(wsb + off);   off += (size_t)ntiles * 4;

  float* out      = (float*)d_out;
  float* unc_out  = out + (size_t)B * C * H * W;
  float* dens_out = unc_out + (size_t)B * H * W;

  prep_kernel<<<dim3((B * N + 255) / 256), 256, 0, stream>>>(
      gd, K, bbox, prm, N, B, (float)W, (float)H);
  tilecull_kernel<<<dim3(H, B), 256, 0, stream>>>(
      bbox, tilelist, tilecnt, N, H, W);
  mlp_kernel<<<dim3((B * N + PTS - 1) / PTS), 256, 0, stream>>>(
      pf, W1, b1, W2, b2, hfe, B * N);
  splat_kernel<<<dim3(NTX, H, B), 256, 0, stream>>>(
      bbox, prm, (const float4*)hfe, tilelist, tilecnt,
      out, unc_out, dens_out, N, C, H, W);
}